// Round 2
// 485.654 us; speedup vs baseline: 1.0391x; 1.0391x over previous
//
#include <hip/hip_runtime.h>

#define NB 16
#define NN 512
#define NP 513   // N+1
#define NM 511   // N-1
#define CFLc 0.5f

#define SE (NP*NP)     // per-batch E
#define SHX (NM*NN)    // per-batch Hx (511 rows x 512 cols)
#define SHY (NN*NM)    // per-batch Hy (512 rows x 511 cols)

// scratch: only the BIG region is used now.
//  amper row-edge partials : [16][16][6][512]  (written K1 part AE-B, read K2)
//  faraday hy-edge partials: [16][16][4][512]  (written K3 part FE-B, read K4)
#define WS_BIG 0
#define WS_SMALL (16*16*6*512)
#define WS_TOT (WS_SMALL + 16*512*6)

__device__ __forceinline__ float dot4(float4 a, float4 b) {
    return a.x*b.x + a.y*b.y + a.z*b.z + a.w*b.w;
}

// load arr4[mb-1 .. mb+3] with zero-fill outside valid range [0,509]
__device__ __forceinline__ void ld5(const float* __restrict__ a, int mb, float4* cr) {
    const float4* a4 = (const float4*)a;
    #pragma unroll
    for (int t = 0; t < 5; t++) {
        int idx = mb - 1 + t;
        if (idx >= 0 && idx <= 509) cr[t] = a4[idx];
        else cr[t] = make_float4(0.f, 0.f, 0.f, 0.f);
    }
}

// ==================================================================
// K1: AE part B (row-edge partials from Hx -> ws)  ||  amper local
//     (LDS-staged stencil + FUSED column-strip reductions from Hy)
// Writes COMPLETE Eout except the row-strip term on rows
// {0,1,2,510,511,512} x cols [2,510], applied by k_fix_e.
// ==================================================================
__global__ __launch_bounds__(512, 4) void k_step1(
    const float* __restrict__ E, const float* __restrict__ Hx, const float* __restrict__ Hy,
    const float* __restrict__ beta, const float* __restrict__ delta,
    const float* __restrict__ fb, const float* __restrict__ fd, const float* __restrict__ fy,
    const float* __restrict__ kf, const float* __restrict__ kb,
    const float* __restrict__ fu, const float* __restrict__ fdn,
    float* __restrict__ ws, float* __restrict__ Eout)
{
    __shared__ float s_hy[7][512];
    __shared__ float s_hx[6][512];
    __shared__ float s_strip[8][6];
    __shared__ float gsm[12];

    int bid = blockIdx.x;
    int tid = threadIdx.x;

    if (bid < 256) {
        // ---------- AE part B: column reductions over Hx ----------
        int b = bid >> 4;
        int chunk = bid & 15;
        int j = tid;
        if (j > 508) return;
        int p0 = chunk * 32;
        int p1 = min(510, p0 + 32);
        const float* Hxb = Hx + (size_t)b*SHX;
        float akf0=0,akf1=0,akb0=0,akb1=0,afu0=0,afu1=0,afd0=0,afd1=0;
        float r0v[4], r1v[4];
        #pragma unroll
        for (int q = 0; q < 4; q++) r0v[q] = Hxb[(size_t)p0*NN + j + q];
        for (int p = p0; p < p1; p++) {
            #pragma unroll
            for (int q = 0; q < 4; q++) r1v[q] = Hxb[(size_t)(p+1)*NN + j + q];
            #pragma unroll
            for (int q = 0; q < 4; q++) {
                float ckf = kf[p*4+q], ckb = kb[p*4+q], cfu = fu[p*4+q], cfd = fdn[p*4+q];
                akf0 += r0v[q]*ckf; akf1 += r1v[q]*ckf;
                akb0 += r0v[q]*ckb; akb1 += r1v[q]*ckb;
                afu0 += r0v[q]*cfu; afu1 += r1v[q]*cfu;
                afd0 += r0v[q]*cfd; afd1 += r1v[q]*cfd;
            }
            #pragma unroll
            for (int q = 0; q < 4; q++) r0v[q] = r1v[q];
        }
        float* o = ws + WS_BIG + (((size_t)b*16 + chunk)*6)*512 + j;
        o[0*512] = akf0;
        o[1*512] = akf1 + afu0;
        o[2*512] = afu1;
        o[3*512] = afd0;
        o[4*512] = afd1 + akb0;
        o[5*512] = akb1;
        return;
    }

    // ---------- amper local (rows r0..r0+3, full width) ----------
    int wrk = bid - 256;                      // 0..2063
    wrk = (wrk & 7) * 258 + (wrk >> 3);       // bijective XCD-chunk swizzle (2064 = 8*258)
    int rg = wrk >> 4;                        // 0..128
    int b  = wrk & 15;
    int r0 = rg * 4;

    const float* Eb  = E  + (size_t)b*SE;
    const float* Hxb = Hx + (size_t)b*SHX;
    const float* Hyb = Hy + (size_t)b*SHY;
    int c = tid;                              // 0..511 (col 512 handled by thread 511)

    if (tid < 12) gsm[tid] = beta[0]*fb[tid] + delta[0]*fd[tid] + fy[tid];
    #pragma unroll
    for (int k = 0; k < 7; k++) {
        int rm = min(max(r0-2+k, 0), 511);
        s_hy[k][c] = Hyb[(size_t)rm*NM + min(c, 510)];
    }
    #pragma unroll
    for (int k = 0; k < 6; k++) {
        int rm = min(max(r0-2+k, 0), 510);
        s_hx[k][c] = Hxb[(size_t)rm*NN + c];
    }
    __syncthreads();

    // ----- fused column-strip dots (replaces k_amper_edges part A) -----
    {
        int w = tid >> 6, lane = tid & 63;
        int jj = w >> 1;                      // output row offset j
        int ii = r0 + jj - 2;                 // strip index i = r-2
        if (ii >= 0 && ii <= 508) {
            int h = w & 1;
            int mb = h*256 + lane*4;          // 4 columns per lane
            float4 hv0 = *(const float4*)&s_hy[jj+0][mb];
            float4 hv1 = *(const float4*)&s_hy[jj+1][mb];
            float4 hv2 = *(const float4*)&s_hy[jj+2][mb];
            float4 hv3 = *(const float4*)&s_hy[jj+3][mb];
            float4 hc0 = make_float4(hv0.x, hv1.x, hv2.x, hv3.x);
            float4 hc1 = make_float4(hv0.y, hv1.y, hv2.y, hv3.y);
            float4 hc2 = make_float4(hv0.z, hv1.z, hv2.z, hv3.z);
            float4 hc3 = make_float4(hv0.w, hv1.w, hv2.w, hv3.w);
            float4 cr[5];
            ld5(kf, mb, cr);
            float pkf0 = dot4(hc0,cr[1]) + dot4(hc1,cr[2]) + dot4(hc2,cr[3]) + dot4(hc3,cr[4]);
            float pkf1 = dot4(hc0,cr[0]) + dot4(hc1,cr[1]) + dot4(hc2,cr[2]) + dot4(hc3,cr[3]);
            ld5(fu, mb, cr);
            float pfu0 = dot4(hc0,cr[1]) + dot4(hc1,cr[2]) + dot4(hc2,cr[3]) + dot4(hc3,cr[4]);
            float pfu1 = dot4(hc0,cr[0]) + dot4(hc1,cr[1]) + dot4(hc2,cr[2]) + dot4(hc3,cr[3]);
            ld5(fdn, mb, cr);
            float pfd0 = dot4(hc0,cr[1]) + dot4(hc1,cr[2]) + dot4(hc2,cr[3]) + dot4(hc3,cr[4]);
            float pfd1 = dot4(hc0,cr[0]) + dot4(hc1,cr[1]) + dot4(hc2,cr[2]) + dot4(hc3,cr[3]);
            ld5(kb, mb, cr);
            float pkb0 = dot4(hc0,cr[1]) + dot4(hc1,cr[2]) + dot4(hc2,cr[3]) + dot4(hc3,cr[4]);
            float pkb1 = dot4(hc0,cr[0]) + dot4(hc1,cr[1]) + dot4(hc2,cr[2]) + dot4(hc3,cr[3]);
            float v0 = pkf0;
            float v1 = pkf1 + pfu0;
            float v2 = pfu1;
            float v3 = pfd0;
            float v4 = pfd1 + pkb0;
            float v5 = pkb1;
            #pragma unroll
            for (int off = 32; off > 0; off >>= 1) {
                v0 += __shfl_down(v0, off);
                v1 += __shfl_down(v1, off);
                v2 += __shfl_down(v2, off);
                v3 += __shfl_down(v3, off);
                v4 += __shfl_down(v4, off);
                v5 += __shfl_down(v5, off);
            }
            if (lane == 0) {
                s_strip[w][0]=v0; s_strip[w][1]=v1; s_strip[w][2]=v2;
                s_strip[w][3]=v3; s_strip[w][4]=v4; s_strip[w][5]=v5;
            }
        }
    }
    __syncthreads();

    float g[12];
    #pragma unroll
    for (int i = 0; i < 12; i++) g[i] = gsm[i];

    int cy0 = min(max(c-2,0),510), cy1 = min(max(c-1,0),510), cy2 = min(c,510);
    int cx0 = max(c-2,0), cx1 = max(c-1,0), cx3 = min(c+1,511);
    float hyv[7][3];
    #pragma unroll
    for (int k = 0; k < 7; k++) {
        hyv[k][0]=s_hy[k][cy0]; hyv[k][1]=s_hy[k][cy1]; hyv[k][2]=s_hy[k][cy2];
    }
    float hxv[6][4];
    #pragma unroll
    for (int k = 0; k < 6; k++) {
        hxv[k][0]=s_hx[k][cx0]; hxv[k][1]=s_hx[k][cx1]; hxv[k][2]=s_hx[k][c]; hxv[k][3]=s_hx[k][cx3];
    }

    bool cint = (c >= 2 && c <= 510);
    int cslot = (c==0)?0:(c==1)?1:(c==2)?2:(c==510)?3:(c==511)?4:-1;
    float* Eo = Eout + (size_t)b*SE;

    #pragma unroll
    for (int j2 = 0; j2 < 4; j2++) {
        int r = r0 + j2;
        if (r > 512) break;            // wave-uniform
        float v = Eb[(size_t)r*NP + c];
        bool rint = (r >= 2 && r <= 510);
        if (rint && cint) {
            float s1 = 0.f, s2 = 0.f;
            #pragma unroll
            for (int p = 0; p < 4; p++)
                s1 += g[p]*hyv[j2+p][0] + g[4+p]*hyv[j2+p][1] + g[8+p]*hyv[j2+p][2];
            #pragma unroll
            for (int p = 0; p < 3; p++)
                s2 += g[p*4+0]*hxv[j2+p][0] + g[p*4+1]*hxv[j2+p][1]
                    + g[p*4+2]*hxv[j2+p][2] + g[p*4+3]*hxv[j2+p][3];
            v += CFLc * (s1 - s2);
        }
        if (rint && cslot >= 0)
            v += CFLc * (s_strip[2*j2][cslot] + s_strip[2*j2+1][cslot]);
        Eo[(size_t)r*NP + c] = v;
        if (c == 511) {                // column 512 (slot 5, no interior/row-strip)
            float v2 = Eb[(size_t)r*NP + 512];
            if (rint) v2 += CFLc * (s_strip[2*j2][5] + s_strip[2*j2+1][5]);
            Eo[(size_t)r*NP + 512] = v2;
        }
    }
}

// ==================================================================
// K2 (tiny): apply deferred row-strip term to Eout rows
// {0,1,2,510,511,512}, cols [2,510].
// ==================================================================
__global__ __launch_bounds__(512) void k_fix_e(
    const float* __restrict__ ws, float* __restrict__ Eout)
{
    int b = blockIdx.y;
    int which = blockIdx.x;                     // == row slot 0..5
    int r = (which < 3) ? which : 507 + which;  // 0,1,2,510,511,512
    int c = 2 + threadIdx.x;
    if (c > 510) return;
    float s = 0.f;
    #pragma unroll
    for (int ch = 0; ch < 16; ch++)
        s += ws[WS_BIG + (((size_t)b*16 + ch)*6 + which)*512 + (c-2)];
    Eout[(size_t)b*SE + (size_t)r*NP + c] -= CFLc * s;
}

// ==================================================================
// K3: FE part B (col partials over E -> ws)  ||  faraday Hx
//     (LDS-staged + FUSED kef/keb row-strips, no scratch)  ||
//     faraday Hy (LDS-staged, row strips deferred to k_fix_hy)
// ==================================================================
__global__ __launch_bounds__(512, 4) void k_step2(
    const float* __restrict__ E, const float* __restrict__ Hx, const float* __restrict__ Hy,
    const float* __restrict__ beta, const float* __restrict__ delta,
    const float* __restrict__ fb, const float* __restrict__ fd, const float* __restrict__ fy,
    const float* __restrict__ kef, const float* __restrict__ keb,
    float* __restrict__ ws, float* __restrict__ Hxout, float* __restrict__ Hyout)
{
    __shared__ float s_e[7][520];
    __shared__ float s_strip2[8][4];
    __shared__ float gsm[12];

    int bid = blockIdx.x;
    int tid = threadIdx.x;

    if (bid < 256) {
        // ---------- FE part B: column reductions over E ----------
        int b = bid >> 4, chunk = bid & 15;
        int c = tid;
        if (c > 510) return;
        int p0 = chunk*32, p1 = p0 + 32;
        const float* Eb = E + (size_t)b*SE;
        float af0=0, af1=0, ab0=0, ab1=0;
        float r0v[3], r1v[3];
        #pragma unroll
        for (int q = 0; q < 3; q++) r0v[q] = Eb[(size_t)p0*NP + c + q];
        for (int p = p0; p < p1; p++) {
            #pragma unroll
            for (int q = 0; q < 3; q++) r1v[q] = Eb[(size_t)(p+1)*NP + c + q];
            float cf0 = kef[p], cf1 = kef[512+p], cf2 = kef[1024+p];
            float cb0 = keb[p], cb1 = keb[512+p], cb2 = keb[1024+p];
            af0 += r0v[0]*cf0 + r0v[1]*cf1 + r0v[2]*cf2;
            af1 += r1v[0]*cf0 + r1v[1]*cf1 + r1v[2]*cf2;
            ab0 += r0v[0]*cb0 + r0v[1]*cb1 + r0v[2]*cb2;
            ab1 += r1v[0]*cb0 + r1v[1]*cb1 + r1v[2]*cb2;
            r0v[0]=r1v[0]; r0v[1]=r1v[1]; r0v[2]=r1v[2];
        }
        float* o = ws + WS_BIG + (((size_t)b*16 + chunk)*4)*512 + c;
        o[0*512] = af0; o[1*512] = af1; o[2*512] = ab0; o[3*512] = ab1;
        return;
    }

    if (tid < 12) gsm[tid] = beta[0]*fb[tid] + delta[0]*fd[tid] + fy[tid];
    int c = tid;

    if (bid < 2304) {
        // ---------- faraday Hx: rows r0..r0+3 (<=510), cols 0..511 ----------
        int wrk = bid - 256;                   // 0..2047
        wrk = (wrk & 7)*256 + (wrk >> 3);      // bijective XCD-chunk swizzle
        int y = wrk >> 4, b = wrk & 15;
        int r0 = y*4;
        const float* Eb = E + (size_t)b*SE;
        #pragma unroll
        for (int k = 0; k < 6; k++) {
            int rm = min(r0+k, 512);
            s_e[k][c] = Eb[(size_t)rm*NP + c];
            if (c == 511) s_e[k][512] = Eb[(size_t)rm*NP + 512];
        }
        __syncthreads();

        // fused kef/keb strips (replaces k_faraday_edges part A)
        {
            int w = tid >> 6, lane = tid & 63;
            int jj = w >> 1, h = w & 1;
            int rr = r0 + jj;
            if (rr <= 510) {
                int mb = h*256 + lane*4;
                int q4 = mb >> 2;
                float4 e0 = *(const float4*)&s_e[jj+0][mb];
                float4 e1 = *(const float4*)&s_e[jj+1][mb];
                float4 e2 = *(const float4*)&s_e[jj+2][mb];
                const float4* kef4 = (const float4*)kef;
                const float4* keb4 = (const float4*)keb;
                float4 f0 = kef4[q4], f1 = kef4[128+q4], f2 = kef4[256+q4];
                float4 b0 = keb4[q4], b1 = keb4[128+q4], b2 = keb4[256+q4];
                float af0 = dot4(e0,f0) + dot4(e1,f1) + dot4(e2,f2);
                float ab0 = dot4(e0,b0) + dot4(e1,b1) + dot4(e2,b2);
                float pw0 = (mb >= 1) ? kef[mb-1]      : 0.f;
                float pw1 = (mb >= 1) ? kef[512+mb-1]  : 0.f;
                float pw2 = (mb >= 1) ? kef[1024+mb-1] : 0.f;
                float af1 = dot4(e0, make_float4(pw0, f0.x, f0.y, f0.z))
                          + dot4(e1, make_float4(pw1, f1.x, f1.y, f1.z))
                          + dot4(e2, make_float4(pw2, f2.x, f2.y, f2.z));
                pw0 = (mb >= 1) ? keb[mb-1]      : 0.f;
                pw1 = (mb >= 1) ? keb[512+mb-1]  : 0.f;
                pw2 = (mb >= 1) ? keb[1024+mb-1] : 0.f;
                float ab1 = dot4(e0, make_float4(pw0, b0.x, b0.y, b0.z))
                          + dot4(e1, make_float4(pw1, b1.x, b1.y, b1.z))
                          + dot4(e2, make_float4(pw2, b2.x, b2.y, b2.z));
                // FIX: the m'=512 term of the shifted outputs (old code looped
                // m < NP=513; lanes above only cover m' in [0,511]). E col 512
                // contributes with coefficient index 511 to af1/ab1.
                if (mb == 508) {
                    float e512_0 = s_e[jj+0][512];
                    float e512_1 = s_e[jj+1][512];
                    float e512_2 = s_e[jj+2][512];
                    af1 += e512_0*kef[511] + e512_1*kef[1023] + e512_2*kef[1535];
                    ab1 += e512_0*keb[511] + e512_1*keb[1023] + e512_2*keb[1535];
                }
                #pragma unroll
                for (int off = 32; off > 0; off >>= 1) {
                    af0 += __shfl_down(af0, off);
                    af1 += __shfl_down(af1, off);
                    ab0 += __shfl_down(ab0, off);
                    ab1 += __shfl_down(ab1, off);
                }
                if (lane == 0) {
                    s_strip2[w][0]=af0; s_strip2[w][1]=af1;
                    s_strip2[w][2]=ab0; s_strip2[w][3]=ab1;
                }
            }
        }
        __syncthreads();

        float g[12];
        #pragma unroll
        for (int i = 0; i < 12; i++) g[i] = gsm[i];
        int c0 = max(c-1,0), c2i = min(c+1,512), c3i = min(c+2,512);
        float ev[6][4];
        #pragma unroll
        for (int k = 0; k < 6; k++) {
            ev[k][0]=s_e[k][c0]; ev[k][1]=s_e[k][c]; ev[k][2]=s_e[k][c2i]; ev[k][3]=s_e[k][c3i];
        }
        bool cint = (c >= 1 && c <= 510);
        int slot = (c==0)?0:(c==1)?1:(c==510)?2:(c==511)?3:-1;
        const float* Hxb = Hx + (size_t)b*SHX;
        float* Ho = Hxout + (size_t)b*SHX;
        #pragma unroll
        for (int j2 = 0; j2 < 4; j2++) {
            int r = r0 + j2;
            if (r > 510) break;        // uniform
            float v = Hxb[(size_t)r*NN + c];
            if (cint) {
                float s = 0.f;
                #pragma unroll
                for (int p = 0; p < 3; p++)
                    s += g[p*4+0]*ev[j2+p][0] + g[p*4+1]*ev[j2+p][1]
                       + g[p*4+2]*ev[j2+p][2] + g[p*4+3]*ev[j2+p][3];
                v -= CFLc * s;
            }
            if (slot >= 0)
                v -= CFLc * (s_strip2[2*j2][slot] + s_strip2[2*j2+1][slot]);
            Ho[(size_t)r*NN + c] = v;
        }
    } else {
        // ---------- faraday Hy: rows r0..r0+3 (<=511), cols 0..510 ----------
        int wrk = bid - 2304;                  // 0..2047
        wrk = (wrk & 7)*256 + (wrk >> 3);
        int y = wrk >> 4, b = wrk & 15;
        int r0 = y*4;
        const float* Eb = E + (size_t)b*SE;
        #pragma unroll
        for (int k = 0; k < 7; k++) {
            int rm = min(max(r0-1+k, 0), 512);
            s_e[k][c] = Eb[(size_t)rm*NP + c];
            if (c == 511) s_e[k][512] = Eb[(size_t)rm*NP + 512];
        }
        __syncthreads();
        if (c > 510) return;

        float g[12];
        #pragma unroll
        for (int i = 0; i < 12; i++) g[i] = gsm[i];
        float ev[7][3];
        #pragma unroll
        for (int k = 0; k < 7; k++) {
            ev[k][0]=s_e[k][c]; ev[k][1]=s_e[k][c+1]; ev[k][2]=s_e[k][c+2];
        }
        const float* Hyb = Hy + (size_t)b*SHY;
        float* Ho = Hyout + (size_t)b*SHY;
        #pragma unroll
        for (int j2 = 0; j2 < 4; j2++) {
            int r = r0 + j2;               // <= 511 always
            float v = Hyb[(size_t)r*NM + c];
            if (r >= 1 && r <= 510) {
                float s = 0.f;
                #pragma unroll
                for (int p = 0; p < 4; p++)
                    s += g[p]*ev[j2+p][0] + g[4+p]*ev[j2+p][1] + g[8+p]*ev[j2+p][2];
                v += CFLc * s;
            }
            Ho[(size_t)r*NM + c] = v;      // strip rows fixed by k_fix_hy
        }
    }
}

// ==================================================================
// K4 (tiny): apply deferred row strips to Hyout rows {0,1,510,511}
// ==================================================================
__global__ __launch_bounds__(512) void k_fix_hy(
    const float* __restrict__ ws, float* __restrict__ Hyout)
{
    int b = blockIdx.y;
    int which = blockIdx.x;                   // == slot 0..3
    int r = (which < 2) ? which : 508 + which; // 0,1,510,511
    int c = threadIdx.x;
    if (c > 510) return;
    float s = 0.f;
    #pragma unroll
    for (int ch = 0; ch < 16; ch++)
        s += ws[WS_BIG + (((size_t)b*16 + ch)*4 + which)*512 + c];
    Hyout[(size_t)b*SHY + (size_t)r*NM + c] += CFLc * s;
}

// ---------------- driver ----------------

static void run_step(const float* Ein, const float* Hxin, const float* Hyin,
                     float* Eout, float* Hxout, float* Hyout, float* ws,
                     const float* beta, const float* delta,
                     const float* fb, const float* fd, const float* fy,
                     const float* kf, const float* kb, const float* fu, const float* fdn,
                     const float* kef, const float* keb, hipStream_t stream)
{
    dim3 blk(512);
    k_step1<<<dim3(256 + 2064), blk, 0, stream>>>(Ein, Hxin, Hyin, beta, delta,
        fb, fd, fy, kf, kb, fu, fdn, ws, Eout);
    k_fix_e<<<dim3(6, NB), blk, 0, stream>>>(ws, Eout);
    k_step2<<<dim3(256 + 2048 + 2048), blk, 0, stream>>>(Eout, Hxin, Hyin, beta, delta,
        fb, fd, fy, kef, keb, ws, Hxout, Hyout);
    k_fix_hy<<<dim3(4, NB), blk, 0, stream>>>(ws, Hyout);
}

extern "C" void kernel_launch(void* const* d_in, const int* in_sizes, int n_in,
                              void* d_out, int out_size, void* d_ws, size_t ws_size,
                              hipStream_t stream)
{
    const float* E1   = (const float*)d_in[0];
    const float* Hx1  = (const float*)d_in[1];
    const float* Hy1  = (const float*)d_in[2];
    const float* beta = (const float*)d_in[9];
    const float* delta= (const float*)d_in[10];
    const float* fb   = (const float*)d_in[11];
    const float* fd   = (const float*)d_in[12];
    const float* fy   = (const float*)d_in[13];
    const float* kf   = (const float*)d_in[14];
    const float* kb   = (const float*)d_in[15];
    const float* fu   = (const float*)d_in[16];
    const float* fdn  = (const float*)d_in[17];
    const float* kef  = (const float*)d_in[18];
    const float* keb  = (const float*)d_in[19];

    float* out = (float*)d_out;
    float* ws  = (float*)d_ws;   // uses WS_BIG region only (~3 MB)
    size_t SEa = (size_t)NB * SE;
    size_t SHa = (size_t)NB * SHX;   // == NB*SHY
    float* E2  = out;
    float* Hx2 = E2  + SEa;
    float* Hy2 = Hx2 + SHa;
    float* E3  = Hy2 + SHa;
    float* Hx3 = E3  + SEa;
    float* Hy3 = Hx3 + SHa;
    float* E4  = Hy3 + SHa;
    float* Hx4 = E4  + SEa;
    float* Hy4 = Hx4 + SHa;

    run_step(E1, Hx1, Hy1, E2, Hx2, Hy2, ws, beta, delta, fb, fd, fy, kf, kb, fu, fdn, kef, keb, stream);
    run_step(E2, Hx2, Hy2, E3, Hx3, Hy3, ws, beta, delta, fb, fd, fy, kf, kb, fu, fdn, kef, keb, stream);
    run_step(E3, Hx3, Hy3, E4, Hx4, Hy4, ws, beta, delta, fb, fd, fy, kf, kb, fu, fdn, kef, keb, stream);
}